// Round 6
// baseline (578.390 us; speedup 1.0000x reference)
//
#include <hip/hip_runtime.h>
#include <math.h>

#define N_NODES   100000
#define N_EDGES   200000
#define NNZ       2000000
#define K_KEEP    1000000
#define BANDCAP   131072
#define TIECAP    4096
// DELTA bounds |p_f32 - p_f64|: f32 pipeline error <= ~3e-6 (64-term dots + mean + W2 dot,
// sigmoid slope 0.25). 1e-4 keeps >30x margin; rescue cost linear in band width.
#define DELTA     1.0e-4f
#define SCAN_BLOCKS 196   // ceil(200000/1024)
#define USCALE (4294967296.0 / 4.0e-3)   // band key -> u32 map; band width < 4e-3 guaranteed

#define SC_PASSES 8
#define SC_EPP    (N_EDGES / SC_PASSES)   // 25000 edges per pass (~2MB vj region, fits XCD L2)
#define SC_BLOCKS 2048                    // 256 blocks per pass

// ---------------- workspace layout (bytes) ----------------
#define OFF_PAB   ((size_t)0)          // float2 p_ab2 [N_NODES*32] 25,600,000 (.x=a_vk, .y=b_vk)
#define OFF_PB32  ((size_t)25600000)   // f32 probs_b [NNZ]        8,000,000 (CSR/p-order probs)
#define OFF_VJ    ((size_t)33600000)   // uint2 vj [NNZ]          16,000,000 (.x=vertex, .y=orig j)
#define OFF_RANK  ((size_t)49600000)   // u32 rank [NNZ] j->rank-in-edge  8,000,000
#define OFF_EOFF  ((size_t)57600000)   // u32 edge_off [N_EDGES]     800,000
#define OFF_CUR   ((size_t)58400000)   // (unused)                   800,000
#define OFF_BS    ((size_t)59200000)   // u32 bsums [256]              1,024
#define OFF_BANDP ((size_t)59201024)   // u32 band_p [BANDCAP]       524,288
#define OFF_BANDJ ((size_t)59725312)   // u32 band_j [BANDCAP]       524,288
#define OFF_BANDE ((size_t)60249600)   // u32 band_e [BANDCAP]       524,288
#define OFF_BANDV ((size_t)60773888)   // u32 band_v [BANDCAP]       524,288
#define OFF_BANDK ((size_t)61298176)   // u64 band_key [BANDCAP]   1,048,576
#define OFF_TIEK  ((size_t)62346752)   // u64 tie_k [TIECAP]          32,768
#define OFF_TIEJ  ((size_t)62379520)   // u32 tie_j [TIECAP]          16,384
#define OFF_TIEP  ((size_t)62395904)   // u32 tie_p [TIECAP]          16,384
// --- zero region ---
#define OFF_FLAG  ((size_t)62412288)   // u8  flag [NNZ]           2,000,000 (0 none, 2 selected)
#define OFF_ECNT  ((size_t)64412288)   // u32 edge_cnt [N_EDGES]     800,000
#define OFF_HIST  ((size_t)65212288)   // u32 hist [4*2048]           32,768
#define OFF_ST    ((size_t)65245056)   // SelState (padded)              256
#define ZERO_OFF  OFF_FLAG
#define ZERO_LEN  ((size_t)(65245312 - 62412288))

// hot atomic counters (n_hi, band_n, tie_n) each on their own 64B line
struct SelState {
    unsigned int B1;        // f32 pass-1 bucket
    unsigned int rem1;      // remaining rank within B1
    float lo_edge, hi_edge; // band boundaries
    unsigned int bB1;       // band-select pass-1 bucket (u32 map, bits 31:21)
    unsigned int brem1;     // remaining rank within bB1
    unsigned int bU0;       // threshold u-bucket base (width 1024)
    unsigned int brem2;     // remaining rank within the u-bucket
    unsigned int _pad0[8];  // -> 64 B
    unsigned int n_hi;      unsigned int _pad1[15];   // own line
    unsigned int band_n;    unsigned int _pad2[15];   // own line
    unsigned int tie_n;     unsigned int _pad3[15];   // own line
};

__device__ __forceinline__ unsigned int band_u32(double key, float lo) {
    double t = (key - (double)lo) * USCALE;
    t = t < 0.0 ? 0.0 : (t > 4294967295.0 ? 4294967295.0 : t);
    return (unsigned int)t;   // monotone non-decreasing in key
}

// p_ab2[v][k] = (sum_d x[v][d]*W1[d][k], sum_d x[v][d]*W1[64+d][k])
__global__ void proj_kernel(const float* __restrict__ x, const float* __restrict__ W1,
                            float2* __restrict__ p_ab2) {
    __shared__ float sW[128 * 32];
    __shared__ float sx[8][64];
    for (int t = threadIdx.x; t < 128 * 32; t += 256) sW[t] = W1[t];
    int base = blockIdx.x * 8;
    for (int t = threadIdx.x; t < 512; t += 256) {
        int n = t >> 6, d = t & 63;
        int g = base + n;
        sx[n][d] = (g < N_NODES) ? x[(size_t)g * 64 + d] : 0.f;
    }
    __syncthreads();
    int ln = threadIdx.x >> 5;
    int k  = threadIdx.x & 31;
    int node = base + ln;
    if (node >= N_NODES) return;
    float sa = 0.f, sb = 0.f;
    for (int d = 0; d < 64; ++d) {
        float xv = sx[ln][d];
        sa += xv * sW[d * 32 + k];
        sb += xv * sW[(64 + d) * 32 + k];
    }
    p_ab2[(size_t)node * 32 + k] = make_float2(sa, sb);
}

// ---------------- CSR build ----------------
// count + rank in one pass: the atomic return IS the within-edge rank.
// 8/thread batching keeps 8 far-atomic returns in flight; rank written coalesced.
__global__ void count_rank_kernel(const int* __restrict__ E, unsigned int* __restrict__ edge_cnt,
                                  unsigned int* __restrict__ rank) {
    unsigned int base = blockIdx.x * 2048 + threadIdx.x;
    int ev[8];
    unsigned int rr[8];
    #pragma unroll
    for (int c = 0; c < 8; ++c) {
        unsigned int j = base + 256u * c;
        if (j < NNZ) ev[c] = E[j];
    }
    #pragma unroll
    for (int c = 0; c < 8; ++c) {
        unsigned int j = base + 256u * c;
        if (j < NNZ) rr[c] = atomicAdd(&edge_cnt[ev[c]], 1u);
    }
    #pragma unroll
    for (int c = 0; c < 8; ++c) {
        unsigned int j = base + 256u * c;
        if (j < NNZ) rank[j] = rr[c];   // coalesced
    }
}

__global__ void scanA_kernel(const unsigned int* __restrict__ edge_cnt,
                             unsigned int* __restrict__ edge_off, unsigned int* __restrict__ bsums) {
    __shared__ unsigned int s[256];
    int tid = threadIdx.x;
    int base = blockIdx.x * 1024 + tid * 4;
    unsigned int v0 = (base + 0 < N_EDGES) ? edge_cnt[base + 0] : 0u;
    unsigned int v1 = (base + 1 < N_EDGES) ? edge_cnt[base + 1] : 0u;
    unsigned int v2 = (base + 2 < N_EDGES) ? edge_cnt[base + 2] : 0u;
    unsigned int v3 = (base + 3 < N_EDGES) ? edge_cnt[base + 3] : 0u;
    unsigned int tsum = v0 + v1 + v2 + v3;
    s[tid] = tsum;
    __syncthreads();
    for (int off = 1; off < 256; off <<= 1) {
        unsigned int t = (tid >= off) ? s[tid - off] : 0u;
        __syncthreads();
        s[tid] += t;
        __syncthreads();
    }
    unsigned int excl = s[tid] - tsum;
    if (base + 0 < N_EDGES) edge_off[base + 0] = excl;
    if (base + 1 < N_EDGES) edge_off[base + 1] = excl + v0;
    if (base + 2 < N_EDGES) edge_off[base + 2] = excl + v0 + v1;
    if (base + 3 < N_EDGES) edge_off[base + 3] = excl + v0 + v1 + v2;
    if (tid == 255) bsums[blockIdx.x] = s[255];
}

__global__ void scanB_kernel(unsigned int* __restrict__ bsums) {
    __shared__ unsigned int s[256];
    int tid = threadIdx.x;
    unsigned int v = (tid < SCAN_BLOCKS) ? bsums[tid] : 0u;
    s[tid] = v;
    __syncthreads();
    for (int off = 1; off < 256; off <<= 1) {
        unsigned int t = (tid >= off) ? s[tid - off] : 0u;
        __syncthreads();
        s[tid] += t;
        __syncthreads();
    }
    if (tid < SCAN_BLOCKS) bsums[tid] = s[tid] - v;
}

__global__ void scanC_kernel(unsigned int* __restrict__ edge_off, const unsigned int* __restrict__ bsums) {
    int i = blockIdx.x * 256 + threadIdx.x;
    if (i >= N_EDGES) return;
    edge_off[i] = edge_off[i] + bsums[i >> 10];
}

// XCD-local CSR scatter: pass p (= blockIdx&7) handles edges [p*SC_EPP, (p+1)*SC_EPP) whose
// vj destination region (~2MB) fits one XCD's 4MB L2 -> scattered 8B writes accumulate into
// full lines before writeback. Nontemporal streaming reads keep dirty vj lines resident.
__global__ void scatter_kernel(const int* __restrict__ V, const int* __restrict__ E,
                               const unsigned int* __restrict__ edge_off,
                               const unsigned int* __restrict__ rank,
                               uint2* __restrict__ vj) {
    unsigned int pass = blockIdx.x & 7u;
    unsigned int q    = blockIdx.x >> 3;
    unsigned int elo  = pass * SC_EPP;
    const unsigned int stride = (SC_BLOCKS / 8) * 256;
    for (unsigned int j = q * 256u + threadIdx.x; j < NNZ; j += stride) {
        unsigned int e = (unsigned int)__builtin_nontemporal_load(E + j);
        if (e - elo < (unsigned int)SC_EPP) {
            unsigned int pp = edge_off[e] + __builtin_nontemporal_load(rank + j);
            unsigned int v  = (unsigned int)__builtin_nontemporal_load(V + j);
            vj[pp] = make_uint2(v, j);
        }
    }
}

// ---------------- fused per-edge mean + per-incidence MLP (f32, CSR-order writes) ----------------
// R6: wave = 2 halves x (2 groups x 16 lanes); ONE EDGE PER HALF. Per-edge prologue/epilogue
// (off/cnt loads, vj preload, prsum reduce, o_ep write) is now amortized over 2 edges per wave
// issue slot; em reduce is one shfl_xor(16) pair. Loop trip = ceil(max(mind0,mind1)/2),
// wave-uniform via shfl_xor(mind,32) BEFORE any divergence. All cross-lane ops stay in
// uniform 16/32-wide segments whose sources are active (R1 lesson). Member-id broadcast via
// per-wave LDS sv[] (exec-mask-safe); a-fragments in registers (aA[16], fully unrolled,
// static indexing).
__global__ void edge_logit_kernel(const uint2* __restrict__ vj,
                                  const unsigned int* __restrict__ edge_off,
                                  const unsigned int* __restrict__ edge_cnt,
                                  const float2* __restrict__ p_ab2,
                                  const float* __restrict__ b1, const float* __restrict__ W2,
                                  const float* __restrict__ b2,
                                  float* __restrict__ probs_b, float* __restrict__ o_ep) {
    __shared__ float slog[4][64];        // [wave][half*32 + slot]
    __shared__ unsigned int sv[4][64];   // [wave][half*32 + slot]
    int w    = threadIdx.x >> 6;
    int lane = threadIdx.x & 63;
    int h    = lane >> 5;                // which edge of the pair
    int hl   = lane & 31;                // lane within half
    int g2   = hl >> 4;                  // group within half: members 2m+g2
    int l    = lane & 15;                // k-pair index: k = 2l, 2l+1
    int e    = blockIdx.x * 8 + w * 2 + h;
    bool ev  = (e < N_EDGES);

    unsigned int off = ev ? edge_off[e] : 0u;
    unsigned int deg = ev ? edge_cnt[e] : 0u;
    unsigned int mind = deg < 32u ? deg : 32u;

    // member-id preload (per half) -> LDS broadcast array
    if ((unsigned int)hl < mind) sv[w][h * 32 + hl] = vj[off + hl].x;

    float2 w2  = ((const float2*)W2)[l];
    float2 bb1 = ((const float2*)b1)[l];
    float  b2v = b2[0];

    // wave-uniform trip bound: max of the two halves' mind (computed pre-divergence)
    unsigned int mind_o = (unsigned int)__shfl_xor((int)mind, 32);
    unsigned int mmax = mind > mind_o ? mind : mind_o;

    // gather: group g2 pulls members 2m+g2 of its half; a-pairs to regs, b-pairs accumulate
    float2 aA[16];
    float2 bacc = make_float2(0.f, 0.f);
    #pragma unroll
    for (unsigned int m = 0; m < 16u; ++m) {
        if (2u * m >= mmax) break;               // wave-uniform exit
        unsigned int idx = 2u * m + (unsigned int)g2;
        if (idx < mind) {
            unsigned int v = sv[w][h * 32 + idx];
            float4 r = reinterpret_cast<const float4*>(p_ab2 + (size_t)v * 32u)[l];
            aA[m] = make_float2(r.x, r.z);
            bacc.x += r.y;
            bacc.y += r.w;
        } else {
            aA[m] = make_float2(0.f, 0.f);
        }
    }
    // deg>32 tail: b only (rare); 2 groups stride the member stream
    for (unsigned int ii = 32u + (unsigned int)g2; ii < deg; ii += 2u) {
        unsigned int v = vj[off + ii].x;
        float4 r = reinterpret_cast<const float4*>(p_ab2 + (size_t)v * 32u)[l];
        bacc.x += r.y;
        bacc.y += r.w;
    }
    // cross-group (within-half) k-wise sum: lane l <-> l+16 of the same half
    bacc.x += __shfl_xor(bacc.x, 16);
    bacc.y += __shfl_xor(bacc.y, 16);
    float cc = (float)(deg > 1u ? deg : 1u);
    float2 em2 = make_float2(bacc.x / cc + bb1.x, bacc.y / cc + bb1.y);

    // logit per member from registers; width-16 reduce serves 4 groups (2 edges) at once
    #pragma unroll
    for (unsigned int m = 0; m < 16u; ++m) {
        if (2u * m >= mmax) break;               // wave-uniform exit
        unsigned int idx = 2u * m + (unsigned int)g2;
        float h0 = aA[m].x + em2.x;
        float h1 = aA[m].y + em2.y;
        h0 = h0 > 0.f ? h0 : 0.f;
        h1 = h1 > 0.f ? h1 : 0.f;
        float t = h0 * w2.x + h1 * w2.y;
        #pragma unroll
        for (int o = 8; o > 0; o >>= 1) t += __shfl_down(t, o, 16);
        if (l == 0 && idx < mind) slog[w][h * 32 + idx] = t;
    }
    // vectorized epilogue: lane hl <-> incidence hl of its half (same wave; LDS ops ordered)
    float prsum = 0.f;
    if ((unsigned int)hl < mind) {
        float pr = 1.f / (1.f + __expf(-(slog[w][h * 32 + hl] + b2v)));
        probs_b[off + hl] = pr;      // coalesced per half
        prsum = pr;
    }
    // deg>32 tail: recompute a from global (rare)
    for (unsigned int ii = 32u + (unsigned int)g2; ii < deg; ii += 2u) {
        unsigned int v = vj[off + ii].x;
        float4 r = reinterpret_cast<const float4*>(p_ab2 + (size_t)v * 32u)[l];
        float h0 = r.x + em2.x;
        float h1 = r.z + em2.y;
        h0 = h0 > 0.f ? h0 : 0.f;
        h1 = h1 > 0.f ? h1 : 0.f;
        float t = h0 * w2.x + h1 * w2.y;
        #pragma unroll
        for (int o = 8; o > 0; o >>= 1) t += __shfl_down(t, o, 16);
        if (l == 0) {
            float pr = 1.f / (1.f + __expf(-(t + b2v)));
            probs_b[off + ii] = pr;
            prsum += pr;
        }
    }
    // per-half reduce (width 32 = the half)
    #pragma unroll
    for (int o = 16; o > 0; o >>= 1) prsum += __shfl_down(prsum, o, 32);
    if (hl == 0 && ev) o_ep[e] = prsum / cc;
}

// ---------------- 2-level radix histogram on f32 keys ----------------
// R6: 4 sub-histograms (tid&3, padded to distinct banks) cut same-address LDS-atomic
// serialization ~4x (probs concentrate in few exponent buckets); float4 loads.
__global__ void hist1_kernel(const float* __restrict__ probs_b, unsigned int* __restrict__ hist) {
    __shared__ unsigned int lh[4][2048 + 8];
    for (int t = threadIdx.x; t < 4 * (2048 + 8); t += 256) ((unsigned int*)lh)[t] = 0;
    __syncthreads();
    int sub = threadIdx.x & 3;
    const float4* p4 = (const float4*)probs_b;
    for (unsigned int i = blockIdx.x * 256 + threadIdx.x; i < NNZ / 4; i += gridDim.x * 256) {
        float4 v = p4[i];
        atomicAdd(&lh[sub][__float_as_uint(v.x) >> 21], 1u);
        atomicAdd(&lh[sub][__float_as_uint(v.y) >> 21], 1u);
        atomicAdd(&lh[sub][__float_as_uint(v.z) >> 21], 1u);
        atomicAdd(&lh[sub][__float_as_uint(v.w) >> 21], 1u);
    }
    __syncthreads();
    for (int t = threadIdx.x; t < 2048; t += 256) {
        unsigned int s = lh[0][t] + lh[1][t] + lh[2][t] + lh[3][t];
        if (s) atomicAdd(&hist[t], s);
    }
}

__global__ void hist2_kernel(const float* __restrict__ probs_b, const SelState* __restrict__ st,
                             unsigned int* __restrict__ hist) {
    __shared__ unsigned int lh[2048];
    for (int t = threadIdx.x; t < 2048; t += 256) lh[t] = 0;
    __syncthreads();
    unsigned int B1 = st->B1;
    for (unsigned int i = blockIdx.x * 256 + threadIdx.x; i < NNZ; i += gridDim.x * 256) {
        unsigned int key = __float_as_uint(probs_b[i]);
        if ((key >> 21) == B1) atomicAdd(&lh[(key >> 10) & 2047u], 1u);
    }
    __syncthreads();
    for (int t = threadIdx.x; t < 2048; t += 256)
        if (lh[t]) atomicAdd(&hist[2048 + t], lh[t]);
}

// which=0: select bucket B1 at rank K_KEEP; which=1: select B2 at rank rem1, set band edges
__global__ void scan_sel_kernel(const unsigned int* __restrict__ hist, SelState* __restrict__ st, int which) {
    __shared__ unsigned int csum[256];
    int t = threadIdx.x;
    unsigned int target = (which == 0) ? (unsigned int)K_KEEP : st->rem1;
    const unsigned int* h = hist + (which ? 2048 : 0);
    unsigned int b[8];
    unsigned int s = 0;
    #pragma unroll
    for (int i = 0; i < 8; ++i) { b[i] = h[t * 8 + i]; s += b[i]; }
    csum[t] = s;
    __syncthreads();
    for (int off = 1; off < 256; off <<= 1) {
        unsigned int v = (t + off < 256) ? csum[t + off] : 0u;
        __syncthreads();
        csum[t] += v;
        __syncthreads();
    }
    unsigned int above = csum[t] - s;       // sum over chunks > t
    if (above < target && target <= above + s) {
        unsigned int rem = target - above;
        unsigned int cum = 0;
        #pragma unroll
        for (int i = 7; i >= 0; --i) {
            if (rem <= cum + b[i]) {
                unsigned int bin = (unsigned int)(t * 8 + i);
                if (which == 0) { st->B1 = bin; st->rem1 = rem - cum; }
                else {
                    unsigned int P = (st->B1 << 21) | (bin << 10);
                    st->lo_edge = __uint_as_float(P) - DELTA;
                    st->hi_edge = __uint_as_float(P + 1024u) + DELTA;
                }
                break;
            }
            cum += b[i];
        }
    }
}

// two-phase fused n_hi count + band append: 1024 grid-stride blocks, 2 global atomics/block
__global__ void bandsel_kernel(const float* __restrict__ probs_b, const int* __restrict__ E,
                               const uint2* __restrict__ vj,
                               SelState* __restrict__ st,
                               unsigned int* __restrict__ band_p, unsigned int* __restrict__ band_j,
                               unsigned int* __restrict__ band_e, unsigned int* __restrict__ band_v) {
    __shared__ unsigned int whi[4], wband[4];
    __shared__ unsigned int sbase, scur;
    float hi = st->hi_edge, lo = st->lo_edge;
    // phase A: local counts
    unsigned int nhi = 0, nband = 0;
    for (unsigned int p = blockIdx.x * 256 + threadIdx.x; p < NNZ; p += gridDim.x * 256) {
        float pk = probs_b[p];
        if (pk > hi) nhi++;
        else if (pk >= lo) nband++;
    }
    #pragma unroll
    for (int o = 32; o > 0; o >>= 1) {
        nhi   += __shfl_down(nhi, o);
        nband += __shfl_down(nband, o);
    }
    if ((threadIdx.x & 63) == 0) { whi[threadIdx.x >> 6] = nhi; wband[threadIdx.x >> 6] = nband; }
    __syncthreads();
    if (threadIdx.x == 0) {
        unsigned int th = whi[0] + whi[1] + whi[2] + whi[3];
        unsigned int tb = wband[0] + wband[1] + wband[2] + wband[3];
        if (th) atomicAdd(&st->n_hi, th);
        sbase = tb ? atomicAdd(&st->band_n, tb) : 0u;
        scur = 0;
    }
    __syncthreads();
    // phase B: append via LDS cursor (order within block arbitrary; selection is key-based)
    for (unsigned int p = blockIdx.x * 256 + threadIdx.x; p < NNZ; p += gridDim.x * 256) {
        float pk = probs_b[p];
        if (pk <= hi && pk >= lo) {
            unsigned int s = sbase + atomicAdd(&scur, 1u);
            if (s < BANDCAP) {
                uint2 t = vj[p];
                band_p[s] = p;
                band_j[s] = t.y;
                band_e[s] = (unsigned int)E[t.y];
                band_v[s] = t.x;
            }
        }
    }
}

// exact f64 recompute for band members; W1 staged in LDS
__global__ void rescue_kernel(const uint2* __restrict__ vj,
                              const unsigned int* __restrict__ edge_off,
                              const unsigned int* __restrict__ edge_cnt,
                              const float* __restrict__ x, const float* __restrict__ W1,
                              const float* __restrict__ b1, const float* __restrict__ W2,
                              const float* __restrict__ b2,
                              const unsigned int* __restrict__ band_e,
                              const unsigned int* __restrict__ band_v,
                              const SelState* __restrict__ st,
                              unsigned long long* __restrict__ band_key) {
    unsigned int n = st->band_n; if (n > BANDCAP) n = BANDCAP;
    if (blockIdx.x * 8 >= n) return;
    __shared__ float sW[128 * 32];
    for (int t = threadIdx.x; t < 128 * 32; t += 256) sW[t] = W1[t];
    __syncthreads();
    unsigned int g = blockIdx.x * 8 + (threadIdx.x >> 5);
    if (g >= n) return;
    int k = threadIdx.x & 31;
    unsigned int v = band_v[g];
    unsigned int e = band_e[g];
    unsigned int off = edge_off[e];
    unsigned int deg = edge_cnt[e];

    const float* xv = x + (size_t)v * 64u;
    double a = 0.0;
    #pragma unroll 8
    for (int d = 0; d < 64; ++d) a += (double)xv[d] * (double)sW[d * 32 + k];
    double bsum = 0.0;
    for (unsigned int m = off; m < off + deg; ++m) {
        const float* xm = x + (size_t)vj[m].x * 64u;
        double acc = 0.0;
        #pragma unroll 8
        for (int d = 0; d < 64; ++d) acc += (double)xm[d] * (double)sW[(64 + d) * 32 + k];
        bsum += acc;
    }
    double cc = (double)(deg > 1u ? deg : 1u);
    double h = a + bsum / cc + (double)b1[k];
    h = h > 0.0 ? h : 0.0;
    double t = h * (double)W2[k];
    #pragma unroll
    for (int o = 16; o > 0; o >>= 1) t += __shfl_down(t, o, 32);
    if (k == 0) {
        double pr = 1.0 / (1.0 + exp(-(t + (double)b2[0])));
        band_key[g] = (unsigned long long)__double_as_longlong(pr);
    }
}

// ---------------- O(n) band selection: 2-level hist on monotone u32 map ----------------
__global__ void bhist1_kernel(const unsigned long long* __restrict__ band_key,
                              const SelState* __restrict__ st, unsigned int* __restrict__ hist) {
    __shared__ unsigned int lh[2048];
    for (int t = threadIdx.x; t < 2048; t += 256) lh[t] = 0;
    __syncthreads();
    unsigned int n = st->band_n; if (n > BANDCAP) n = BANDCAP;
    float lo = st->lo_edge;
    for (unsigned int i = blockIdx.x * 256 + threadIdx.x; i < n; i += gridDim.x * 256) {
        unsigned int u = band_u32(__longlong_as_double((long long)band_key[i]), lo);
        atomicAdd(&lh[u >> 21], 1u);
    }
    __syncthreads();
    for (int t = threadIdx.x; t < 2048; t += 256)
        if (lh[t]) atomicAdd(&hist[4096 + t], lh[t]);
}

__global__ void bhist2_kernel(const unsigned long long* __restrict__ band_key,
                              const SelState* __restrict__ st, unsigned int* __restrict__ hist) {
    __shared__ unsigned int lh[2048];
    for (int t = threadIdx.x; t < 2048; t += 256) lh[t] = 0;
    __syncthreads();
    unsigned int n = st->band_n; if (n > BANDCAP) n = BANDCAP;
    float lo = st->lo_edge;
    unsigned int bB1 = st->bB1;
    for (unsigned int i = blockIdx.x * 256 + threadIdx.x; i < n; i += gridDim.x * 256) {
        unsigned int u = band_u32(__longlong_as_double((long long)band_key[i]), lo);
        if ((u >> 21) == bB1) atomicAdd(&lh[(u >> 10) & 2047u], 1u);
    }
    __syncthreads();
    for (int t = threadIdx.x; t < 2048; t += 256)
        if (lh[t]) atomicAdd(&hist[6144 + t], lh[t]);
}

// which=0: bucket bB1 at rank (K_KEEP - n_hi); which=1: bucket bB2 at rank brem1 -> bU0, brem2
__global__ void bscan_kernel(const unsigned int* __restrict__ hist, SelState* __restrict__ st, int which) {
    __shared__ unsigned int csum[256];
    int t = threadIdx.x;
    unsigned int target = (which == 0) ? ((unsigned int)K_KEEP - st->n_hi) : st->brem1;
    const unsigned int* h = hist + (which ? 6144 : 4096);
    unsigned int b[8];
    unsigned int s = 0;
    #pragma unroll
    for (int i = 0; i < 8; ++i) { b[i] = h[t * 8 + i]; s += b[i]; }
    csum[t] = s;
    __syncthreads();
    for (int off = 1; off < 256; off <<= 1) {
        unsigned int v = (t + off < 256) ? csum[t + off] : 0u;
        __syncthreads();
        csum[t] += v;
        __syncthreads();
    }
    unsigned int above = csum[t] - s;
    if (above < target && target <= above + s) {
        unsigned int rem = target - above;
        unsigned int cum = 0;
        #pragma unroll
        for (int i = 7; i >= 0; --i) {
            if (rem <= cum + b[i]) {
                unsigned int bin = (unsigned int)(t * 8 + i);
                if (which == 0) { st->bB1 = bin; st->brem1 = rem - cum; }
                else            { st->bU0 = (st->bB1 << 21) | (bin << 10); st->brem2 = rem - cum; }
                break;
            }
            cum += b[i];
        }
    }
}

// mark u >= bU0+1024 selected; collect tie bucket [bU0, bU0+1024)
__global__ void btie_kernel(const unsigned long long* __restrict__ band_key,
                            const unsigned int* __restrict__ band_j,
                            const unsigned int* __restrict__ band_p,
                            SelState* __restrict__ st, unsigned char* __restrict__ flag,
                            unsigned long long* __restrict__ tie_k,
                            unsigned int* __restrict__ tie_j, unsigned int* __restrict__ tie_p) {
    unsigned int n = st->band_n; if (n > BANDCAP) n = BANDCAP;
    unsigned int i = blockIdx.x * 256 + threadIdx.x;
    if (i >= n) return;
    float lo = st->lo_edge;
    unsigned int U0 = st->bU0;
    unsigned long long key = band_key[i];
    unsigned int u = band_u32(__longlong_as_double((long long)key), lo);
    if (u >= U0 + 1024u) {
        flag[band_p[i]] = 2u;
    } else if (u >= U0) {
        unsigned int s = atomicAdd(&st->tie_n, 1u);
        if (s < TIECAP) { tie_k[s] = key; tie_j[s] = band_j[i]; tie_p[s] = band_p[i]; }
    }
}

// exact rank inside the (tiny) tie bucket by (key desc, j asc); take first brem2
__global__ void btierank_kernel(const unsigned long long* __restrict__ tie_k,
                                const unsigned int* __restrict__ tie_j,
                                const unsigned int* __restrict__ tie_p,
                                const SelState* __restrict__ st, unsigned char* __restrict__ flag) {
    unsigned int n = st->tie_n; if (n > TIECAP) n = TIECAP;
    unsigned int need = st->brem2;
    for (unsigned int i = threadIdx.x; i < n; i += 256) {
        unsigned long long ki = tie_k[i];
        unsigned int ji = tie_j[i];
        unsigned int r = 0;
        for (unsigned int q = 0; q < n; ++q) {
            unsigned long long kq = tie_k[q];
            if (kq > ki || (kq == ki && tie_j[q] < ji)) r++;
        }
        if (r < need) flag[tie_p[i]] = 2u;
    }
}

// j-order coalesced outputs; p recomputed as edge_off[E[j]] + rank[j].
// R6: 4 j's per thread -> 4 independent edge_off/probs/flag gathers in flight; float4 stores.
__global__ void out_kernel(const float* __restrict__ probs_b, const unsigned char* __restrict__ flag,
                           const int* __restrict__ E, const unsigned int* __restrict__ rank,
                           const unsigned int* __restrict__ edge_off, const SelState* __restrict__ st,
                           float* __restrict__ o_probs, float* __restrict__ o_soft, float* __restrict__ o_hard) {
    unsigned int j0 = (blockIdx.x * 256 + threadIdx.x) * 4u;
    if (j0 >= NNZ) return;   // NNZ % 4 == 0, full vectors only
    float hi = st->hi_edge;
    int4  e4 = *reinterpret_cast<const int4*>(E + j0);
    uint4 r4 = *reinterpret_cast<const uint4*>(rank + j0);
    unsigned int p0 = edge_off[e4.x] + r4.x;
    unsigned int p1 = edge_off[e4.y] + r4.y;
    unsigned int p2 = edge_off[e4.z] + r4.z;
    unsigned int p3 = edge_off[e4.w] + r4.w;
    float pk0 = probs_b[p0], pk1 = probs_b[p1], pk2 = probs_b[p2], pk3 = probs_b[p3];
    unsigned char f0 = flag[p0], f1 = flag[p1], f2 = flag[p2], f3 = flag[p3];
    float4 pr = make_float4(pk0, pk1, pk2, pk3);
    float4 hb = make_float4((pk0 > hi || f0 == 2u) ? 1.f : 0.f,
                            (pk1 > hi || f1 == 2u) ? 1.f : 0.f,
                            (pk2 > hi || f2 == 2u) ? 1.f : 0.f,
                            (pk3 > hi || f3 == 2u) ? 1.f : 0.f);
    *reinterpret_cast<float4*>(o_probs + j0) = pr;
    *reinterpret_cast<float4*>(o_soft  + j0) = hb;
    *reinterpret_cast<float4*>(o_hard  + j0) = hb;
}

// per-edge: edge_soft / edge_hard recomputed from CSR-coalesced probs/flag
__global__ void edge_out_kernel(const float* __restrict__ probs_b, const unsigned char* __restrict__ flag,
                                const unsigned int* __restrict__ edge_off,
                                const unsigned int* __restrict__ edge_cnt,
                                const SelState* __restrict__ st,
                                float* __restrict__ o_es, float* __restrict__ o_eh) {
    unsigned int e = blockIdx.x * 256 + threadIdx.x;
    if (e >= N_EDGES) return;
    float hi = st->hi_edge;
    unsigned int off = edge_off[e], deg = edge_cnt[e];
    unsigned int cnt = 0;
    for (unsigned int i = 0; i < deg; ++i)
        cnt += (probs_b[off + i] > hi || flag[off + i] == 2u) ? 1u : 0u;
    float cc = (float)(deg > 1u ? deg : 1u);
    o_es[e] = (float)cnt / cc;
    o_eh[e] = cnt ? 1.f : 0.f;
}

extern "C" void kernel_launch(void* const* d_in, const int* in_sizes, int n_in,
                              void* d_out, int out_size, void* d_ws, size_t ws_size,
                              hipStream_t stream) {
    const float* x  = (const float*)d_in[0];
    const int*   V  = (const int*)d_in[1];
    const int*   E  = (const int*)d_in[2];
    const float* W1 = (const float*)d_in[3];
    const float* b1 = (const float*)d_in[4];
    const float* W2 = (const float*)d_in[5];
    const float* b2 = (const float*)d_in[6];

    float* out     = (float*)d_out;
    float* o_probs = out;
    float* o_soft  = out + NNZ;
    float* o_hard  = out + 2 * (size_t)NNZ;
    float* o_ep    = out + 3 * (size_t)NNZ;
    float* o_es    = out + 3 * (size_t)NNZ + N_EDGES;
    float* o_eh    = out + 3 * (size_t)NNZ + 2 * (size_t)N_EDGES;

    char* w = (char*)d_ws;
    float2*             p_ab2    = (float2*)(w + OFF_PAB);
    float*              probs_b  = (float*)(w + OFF_PB32);
    uint2*              vj       = (uint2*)(w + OFF_VJ);
    unsigned int*       rank     = (unsigned int*)(w + OFF_RANK);
    unsigned int*       edge_off = (unsigned int*)(w + OFF_EOFF);
    unsigned int*       bsums    = (unsigned int*)(w + OFF_BS);
    unsigned int*       band_p   = (unsigned int*)(w + OFF_BANDP);
    unsigned int*       band_j   = (unsigned int*)(w + OFF_BANDJ);
    unsigned int*       band_e   = (unsigned int*)(w + OFF_BANDE);
    unsigned int*       band_v   = (unsigned int*)(w + OFF_BANDV);
    unsigned long long* band_key = (unsigned long long*)(w + OFF_BANDK);
    unsigned long long* tie_k    = (unsigned long long*)(w + OFF_TIEK);
    unsigned int*       tie_j    = (unsigned int*)(w + OFF_TIEJ);
    unsigned int*       tie_p    = (unsigned int*)(w + OFF_TIEP);
    unsigned char*      flag     = (unsigned char*)(w + OFF_FLAG);
    unsigned int*       edge_cnt = (unsigned int*)(w + OFF_ECNT);
    unsigned int*       hist     = (unsigned int*)(w + OFF_HIST);
    SelState*           st       = (SelState*)(w + OFF_ST);

    hipMemsetAsync(w + ZERO_OFF, 0, ZERO_LEN, stream);

    proj_kernel<<<(N_NODES + 7) / 8, 256, 0, stream>>>(x, W1, p_ab2);

    count_rank_kernel<<<(NNZ + 2047) / 2048, 256, 0, stream>>>(E, edge_cnt, rank);
    scanA_kernel<<<SCAN_BLOCKS, 256, 0, stream>>>(edge_cnt, edge_off, bsums);
    scanB_kernel<<<1, 256, 0, stream>>>(bsums);
    scanC_kernel<<<(N_EDGES + 255) / 256, 256, 0, stream>>>(edge_off, bsums);
    scatter_kernel<<<SC_BLOCKS, 256, 0, stream>>>(V, E, edge_off, rank, vj);

    edge_logit_kernel<<<(N_EDGES + 7) / 8, 256, 0, stream>>>(vj, edge_off, edge_cnt,
                                                             p_ab2, b1, W2, b2, probs_b, o_ep);

    hist1_kernel<<<1024, 256, 0, stream>>>(probs_b, hist);
    scan_sel_kernel<<<1, 256, 0, stream>>>(hist, st, 0);
    hist2_kernel<<<1024, 256, 0, stream>>>(probs_b, st, hist);
    scan_sel_kernel<<<1, 256, 0, stream>>>(hist, st, 1);

    bandsel_kernel<<<1024, 256, 0, stream>>>(probs_b, E, vj, st,
                                             band_p, band_j, band_e, band_v);
    rescue_kernel<<<BANDCAP / 8, 256, 0, stream>>>(vj, edge_off, edge_cnt, x, W1, b1, W2, b2,
                                                   band_e, band_v, st, band_key);

    bhist1_kernel<<<64, 256, 0, stream>>>(band_key, st, hist);
    bscan_kernel<<<1, 256, 0, stream>>>(hist, st, 0);
    bhist2_kernel<<<64, 256, 0, stream>>>(band_key, st, hist);
    bscan_kernel<<<1, 256, 0, stream>>>(hist, st, 1);
    btie_kernel<<<BANDCAP / 256, 256, 0, stream>>>(band_key, band_j, band_p, st, flag,
                                                   tie_k, tie_j, tie_p);
    btierank_kernel<<<1, 256, 0, stream>>>(tie_k, tie_j, tie_p, st, flag);

    out_kernel<<<(NNZ / 4 + 255) / 256, 256, 0, stream>>>(probs_b, flag, E, rank, edge_off, st,
                                                          o_probs, o_soft, o_hard);
    edge_out_kernel<<<(N_EDGES + 255) / 256, 256, 0, stream>>>(probs_b, flag, edge_off, edge_cnt, st,
                                                               o_es, o_eh);
}

// Round 7
// 556.734 us; speedup vs baseline: 1.0389x; 1.0389x over previous
//
#include <hip/hip_runtime.h>
#include <math.h>

#define N_NODES   100000
#define N_EDGES   200000
#define NNZ       2000000
#define K_KEEP    1000000
#define BANDCAP   131072
#define TIECAP    4096
// DELTA bounds |p_f32 - p_f64|: f32 pipeline error <= ~3e-6 (64-term dots + mean + W2 dot,
// sigmoid slope 0.25). 1e-4 keeps >30x margin; rescue cost linear in band width.
#define DELTA     1.0e-4f
#define SCAN_BLOCKS 196   // ceil(200000/1024)
#define USCALE (4294967296.0 / 4.0e-3)   // band key -> u32 map; band width < 4e-3 guaranteed

#define SC_PASSES 8
#define SC_EPP    (N_EDGES / SC_PASSES)   // 25000 edges per pass (~2MB vj region, fits XCD L2)
#define SC_BLOCKS 2048                    // 256 blocks per pass

// ---------------- workspace layout (bytes) ----------------
#define OFF_PAB   ((size_t)0)          // float2 p_ab2 [N_NODES*32] 25,600,000 (.x=a_vk, .y=b_vk)
#define OFF_PB32  ((size_t)25600000)   // f32 probs_b [NNZ]        8,000,000 (CSR/p-order probs)
#define OFF_VJ    ((size_t)33600000)   // uint2 vj [NNZ]          16,000,000 (.x=vertex, .y=orig j)
#define OFF_RANK  ((size_t)49600000)   // u32 rank [NNZ] j->rank-in-edge  8,000,000
#define OFF_EOFF  ((size_t)57600000)   // u32 edge_off [N_EDGES]     800,000
#define OFF_CUR   ((size_t)58400000)   // (unused)                   800,000
#define OFF_BS    ((size_t)59200000)   // u32 bsums [256]              1,024
#define OFF_BANDP ((size_t)59201024)   // u32 band_p [BANDCAP]       524,288
#define OFF_BANDJ ((size_t)59725312)   // u32 band_j [BANDCAP]       524,288
#define OFF_BANDE ((size_t)60249600)   // u32 band_e [BANDCAP]       524,288
#define OFF_BANDV ((size_t)60773888)   // u32 band_v [BANDCAP]       524,288
#define OFF_BANDK ((size_t)61298176)   // u64 band_key [BANDCAP]   1,048,576
#define OFF_TIEK  ((size_t)62346752)   // u64 tie_k [TIECAP]          32,768
#define OFF_TIEJ  ((size_t)62379520)   // u32 tie_j [TIECAP]          16,384
#define OFF_TIEP  ((size_t)62395904)   // u32 tie_p [TIECAP]          16,384
// --- zero region ---
#define OFF_FLAG  ((size_t)62412288)   // u8  flag [NNZ]           2,000,000 (0 none, 2 selected)
#define OFF_ECNT  ((size_t)64412288)   // u32 edge_cnt [N_EDGES]     800,000
#define OFF_HIST  ((size_t)65212288)   // u32 hist [4*2048]           32,768
#define OFF_ST    ((size_t)65245056)   // SelState (padded)              256
#define ZERO_OFF  OFF_FLAG
#define ZERO_LEN  ((size_t)(65245312 - 62412288))

// hot atomic counters (n_hi, band_n, tie_n) each on their own 64B line
struct SelState {
    unsigned int B1;        // (unused after R7 inlining)
    unsigned int rem1;      // (unused)
    float lo_edge, hi_edge; // band boundaries (written redundantly by bandsel blocks)
    unsigned int bB1;       // (unused)
    unsigned int brem1;     // (unused)
    unsigned int bU0;       // threshold u-bucket base (written redundantly by btie blocks)
    unsigned int brem2;     // remaining rank within the u-bucket (written by btie)
    unsigned int _pad0[8];  // -> 64 B
    unsigned int n_hi;      unsigned int _pad1[15];   // own line
    unsigned int band_n;    unsigned int _pad2[15];   // own line
    unsigned int tie_n;     unsigned int _pad3[15];   // own line
};

__device__ __forceinline__ unsigned int band_u32(double key, float lo) {
    double t = (key - (double)lo) * USCALE;
    t = t < 0.0 ? 0.0 : (t > 4294967295.0 ? 4294967295.0 : t);
    return (unsigned int)t;   // monotone non-decreasing in key
}

// p_ab2[v][k] = (sum_d x[v][d]*W1[d][k], sum_d x[v][d]*W1[64+d][k])
__global__ void proj_kernel(const float* __restrict__ x, const float* __restrict__ W1,
                            float2* __restrict__ p_ab2) {
    __shared__ float sW[128 * 32];
    __shared__ float sx[8][64];
    for (int t = threadIdx.x; t < 128 * 32; t += 256) sW[t] = W1[t];
    int base = blockIdx.x * 8;
    for (int t = threadIdx.x; t < 512; t += 256) {
        int n = t >> 6, d = t & 63;
        int g = base + n;
        sx[n][d] = (g < N_NODES) ? x[(size_t)g * 64 + d] : 0.f;
    }
    __syncthreads();
    int ln = threadIdx.x >> 5;
    int k  = threadIdx.x & 31;
    int node = base + ln;
    if (node >= N_NODES) return;
    float sa = 0.f, sb = 0.f;
    for (int d = 0; d < 64; ++d) {
        float xv = sx[ln][d];
        sa += xv * sW[d * 32 + k];
        sb += xv * sW[(64 + d) * 32 + k];
    }
    p_ab2[(size_t)node * 32 + k] = make_float2(sa, sb);
}

// ---------------- CSR build ----------------
// count + rank in one pass: the atomic return IS the within-edge rank.
__global__ void count_rank_kernel(const int* __restrict__ E, unsigned int* __restrict__ edge_cnt,
                                  unsigned int* __restrict__ rank) {
    unsigned int base = blockIdx.x * 2048 + threadIdx.x;
    int ev[8];
    unsigned int rr[8];
    #pragma unroll
    for (int c = 0; c < 8; ++c) {
        unsigned int j = base + 256u * c;
        if (j < NNZ) ev[c] = E[j];
    }
    #pragma unroll
    for (int c = 0; c < 8; ++c) {
        unsigned int j = base + 256u * c;
        if (j < NNZ) rr[c] = atomicAdd(&edge_cnt[ev[c]], 1u);
    }
    #pragma unroll
    for (int c = 0; c < 8; ++c) {
        unsigned int j = base + 256u * c;
        if (j < NNZ) rank[j] = rr[c];   // coalesced
    }
}

__global__ void scanA_kernel(const unsigned int* __restrict__ edge_cnt,
                             unsigned int* __restrict__ edge_off, unsigned int* __restrict__ bsums) {
    __shared__ unsigned int s[256];
    int tid = threadIdx.x;
    int base = blockIdx.x * 1024 + tid * 4;
    unsigned int v0 = (base + 0 < N_EDGES) ? edge_cnt[base + 0] : 0u;
    unsigned int v1 = (base + 1 < N_EDGES) ? edge_cnt[base + 1] : 0u;
    unsigned int v2 = (base + 2 < N_EDGES) ? edge_cnt[base + 2] : 0u;
    unsigned int v3 = (base + 3 < N_EDGES) ? edge_cnt[base + 3] : 0u;
    unsigned int tsum = v0 + v1 + v2 + v3;
    s[tid] = tsum;
    __syncthreads();
    for (int off = 1; off < 256; off <<= 1) {
        unsigned int t = (tid >= off) ? s[tid - off] : 0u;
        __syncthreads();
        s[tid] += t;
        __syncthreads();
    }
    unsigned int excl = s[tid] - tsum;
    if (base + 0 < N_EDGES) edge_off[base + 0] = excl;
    if (base + 1 < N_EDGES) edge_off[base + 1] = excl + v0;
    if (base + 2 < N_EDGES) edge_off[base + 2] = excl + v0 + v1;
    if (base + 3 < N_EDGES) edge_off[base + 3] = excl + v0 + v1 + v2;
    if (tid == 255) bsums[blockIdx.x] = s[255];
}

__global__ void scanB_kernel(unsigned int* __restrict__ bsums) {
    __shared__ unsigned int s[256];
    int tid = threadIdx.x;
    unsigned int v = (tid < SCAN_BLOCKS) ? bsums[tid] : 0u;
    s[tid] = v;
    __syncthreads();
    for (int off = 1; off < 256; off <<= 1) {
        unsigned int t = (tid >= off) ? s[tid - off] : 0u;
        __syncthreads();
        s[tid] += t;
        __syncthreads();
    }
    if (tid < SCAN_BLOCKS) bsums[tid] = s[tid] - v;
}

__global__ void scanC_kernel(unsigned int* __restrict__ edge_off, const unsigned int* __restrict__ bsums) {
    int i = blockIdx.x * 256 + threadIdx.x;
    if (i >= N_EDGES) return;
    edge_off[i] = edge_off[i] + bsums[i >> 10];
}

// XCD-local CSR scatter (see R3): pass p = blockIdx&7 handles a ~2MB vj region per XCD L2.
__global__ void scatter_kernel(const int* __restrict__ V, const int* __restrict__ E,
                               const unsigned int* __restrict__ edge_off,
                               const unsigned int* __restrict__ rank,
                               uint2* __restrict__ vj) {
    unsigned int pass = blockIdx.x & 7u;
    unsigned int q    = blockIdx.x >> 3;
    unsigned int elo  = pass * SC_EPP;
    const unsigned int stride = (SC_BLOCKS / 8) * 256;
    for (unsigned int j = q * 256u + threadIdx.x; j < NNZ; j += stride) {
        unsigned int e = (unsigned int)__builtin_nontemporal_load(E + j);
        if (e - elo < (unsigned int)SC_EPP) {
            unsigned int pp = edge_off[e] + __builtin_nontemporal_load(rank + j);
            unsigned int v  = (unsigned int)__builtin_nontemporal_load(V + j);
            vj[pp] = make_uint2(v, j);
        }
    }
}

// ---------------- fused per-edge mean + per-incidence MLP (R5 structure, reverted) ----------
// Wave = 4 groups x 16 lanes, ONE edge per wave (R6's 2-edge pairing regressed: +16 VGPR and
// max-coupled trip counts dropped occupancy 76->47% and flipped the kernel latency-bound).
// Lane l of group g holds k-pair (2l,2l+1); group g owns members 4m+g; float4 gather;
// a-fragments in registers; width-16 reduce serves 4 incidences per instruction.
__global__ void edge_logit_kernel(const uint2* __restrict__ vj,
                                  const unsigned int* __restrict__ edge_off,
                                  const unsigned int* __restrict__ edge_cnt,
                                  const float2* __restrict__ p_ab2,
                                  const float* __restrict__ b1, const float* __restrict__ W2,
                                  const float* __restrict__ b2,
                                  float* __restrict__ probs_b, float* __restrict__ o_ep) {
    __shared__ float slog[4][32];        // per-incidence logits
    __shared__ unsigned int sv[4][32];   // per-wave member-id broadcast (exec-mask-safe)
    int e = blockIdx.x * 4 + (threadIdx.x >> 6);
    if (e >= N_EDGES) return;
    int w    = threadIdx.x >> 6;
    int lane = threadIdx.x & 63;
    int g    = lane >> 4;                // member-slot group 0..3
    int l    = lane & 15;                // k-pair index: k = 2l, 2l+1

    unsigned int off = edge_off[e];
    unsigned int deg = edge_cnt[e];
    unsigned int mind = deg < 32u ? deg : 32u;

    if ((unsigned int)lane < mind) sv[w][lane] = vj[off + lane].x;

    float2 w2  = ((const float2*)W2)[l];
    float2 bb1 = ((const float2*)b1)[l];
    float  b2v = b2[0];

    float2 aA[8];
    float2 bacc = make_float2(0.f, 0.f);
    #pragma unroll 8
    for (unsigned int m = 0; m < 8u; ++m) {
        if (4u * m >= mind) break;               // wave-uniform exit
        unsigned int idx = 4u * m + (unsigned int)g;
        if (idx < mind) {
            unsigned int v = sv[w][idx];
            float4 r = reinterpret_cast<const float4*>(p_ab2 + (size_t)v * 32u)[l];
            aA[m] = make_float2(r.x, r.z);
            bacc.x += r.y;
            bacc.y += r.w;
        } else {
            aA[m] = make_float2(0.f, 0.f);
        }
    }
    for (unsigned int ii = 32u + (unsigned int)g; ii < deg; ii += 4u) {   // deg>32 tail: b only
        unsigned int v = vj[off + ii].x;
        float4 r = reinterpret_cast<const float4*>(p_ab2 + (size_t)v * 32u)[l];
        bacc.x += r.y;
        bacc.y += r.w;
    }
    bacc.x += __shfl_xor(bacc.x, 16);
    bacc.y += __shfl_xor(bacc.y, 16);
    bacc.x += __shfl_xor(bacc.x, 32);
    bacc.y += __shfl_xor(bacc.y, 32);
    float cc = (float)(deg > 1u ? deg : 1u);
    float2 em2 = make_float2(bacc.x / cc + bb1.x, bacc.y / cc + bb1.y);

    #pragma unroll 8
    for (unsigned int m = 0; m < 8u; ++m) {
        if (4u * m >= mind) break;               // wave-uniform exit
        unsigned int idx = 4u * m + (unsigned int)g;
        float h0 = aA[m].x + em2.x;
        float h1 = aA[m].y + em2.y;
        h0 = h0 > 0.f ? h0 : 0.f;
        h1 = h1 > 0.f ? h1 : 0.f;
        float t = h0 * w2.x + h1 * w2.y;
        #pragma unroll
        for (int o = 8; o > 0; o >>= 1) t += __shfl_down(t, o, 16);
        if (l == 0 && idx < mind) slog[w][idx] = t;
    }
    float prsum = 0.f;
    if ((unsigned int)lane < mind) {
        float pr = 1.f / (1.f + __expf(-(slog[w][lane] + b2v)));
        probs_b[off + lane] = pr;      // coalesced
        prsum = pr;
    }
    for (unsigned int ii = 32u + (unsigned int)g; ii < deg; ii += 4u) {   // deg>32 tail
        unsigned int v = vj[off + ii].x;
        float4 r = reinterpret_cast<const float4*>(p_ab2 + (size_t)v * 32u)[l];
        float h0 = r.x + em2.x;
        float h1 = r.z + em2.y;
        h0 = h0 > 0.f ? h0 : 0.f;
        h1 = h1 > 0.f ? h1 : 0.f;
        float t = h0 * w2.x + h1 * w2.y;
        #pragma unroll
        for (int o = 8; o > 0; o >>= 1) t += __shfl_down(t, o, 16);
        if (l == 0) {
            float pr = 1.f / (1.f + __expf(-(t + b2v)));
            probs_b[off + ii] = pr;
            prsum += pr;
        }
    }
    #pragma unroll
    for (int o = 32; o > 0; o >>= 1) prsum += __shfl_down(prsum, o, 64);
    if (lane == 0) o_ep[e] = prsum / cc;
}

// ---------------- radix-scan helper (inlined redundantly per block; R7) ----------------
// Finds the bin (descending order) containing rank `target` in a 2048-bin histogram h[],
// broadcasting {bin, rem} to all 256 threads via LDS. csum/sres are caller-provided LDS.
__device__ __forceinline__ void radix_sel_256(const unsigned int* __restrict__ h,
                                              unsigned int target,
                                              unsigned int* csum, unsigned int* sres,
                                              unsigned int& out_bin, unsigned int& out_rem) {
    int t = threadIdx.x;
    unsigned int b[8];
    unsigned int s = 0;
    #pragma unroll
    for (int i = 0; i < 8; ++i) { b[i] = h[t * 8 + i]; s += b[i]; }
    csum[t] = s;
    __syncthreads();
    for (int off = 1; off < 256; off <<= 1) {
        unsigned int v = (t + off < 256) ? csum[t + off] : 0u;
        __syncthreads();
        csum[t] += v;
        __syncthreads();
    }
    unsigned int above = csum[t] - s;       // sum over chunks > t
    if (above < target && target <= above + s) {
        unsigned int rem = target - above;
        unsigned int cum = 0;
        #pragma unroll
        for (int i = 7; i >= 0; --i) {
            if (rem <= cum + b[i]) {
                sres[0] = (unsigned int)(t * 8 + i);
                sres[1] = rem - cum;
                break;
            }
            cum += b[i];
        }
    }
    __syncthreads();
    out_bin = sres[0];
    out_rem = sres[1];
    __syncthreads();
}

// ---------------- 2-level radix histogram on f32 keys ----------------
// 4 sub-histograms (tid&3, padded) cut same-address LDS-atomic serialization; float4 loads.
__global__ void hist1_kernel(const float* __restrict__ probs_b, unsigned int* __restrict__ hist) {
    __shared__ unsigned int lh[4][2048 + 8];
    for (int t = threadIdx.x; t < 4 * (2048 + 8); t += 256) ((unsigned int*)lh)[t] = 0;
    __syncthreads();
    int sub = threadIdx.x & 3;
    const float4* p4 = (const float4*)probs_b;
    for (unsigned int i = blockIdx.x * 256 + threadIdx.x; i < NNZ / 4; i += gridDim.x * 256) {
        float4 v = p4[i];
        atomicAdd(&lh[sub][__float_as_uint(v.x) >> 21], 1u);
        atomicAdd(&lh[sub][__float_as_uint(v.y) >> 21], 1u);
        atomicAdd(&lh[sub][__float_as_uint(v.z) >> 21], 1u);
        atomicAdd(&lh[sub][__float_as_uint(v.w) >> 21], 1u);
    }
    __syncthreads();
    for (int t = threadIdx.x; t < 2048; t += 256) {
        unsigned int s = lh[0][t] + lh[1][t] + lh[2][t] + lh[3][t];
        if (s) atomicAdd(&hist[t], s);
    }
}

// R7: level-1 selection (old scan_sel which=0) inlined — each block recomputes B1 from hist.
__global__ void hist2_kernel(const float* __restrict__ probs_b,
                             const unsigned int* __restrict__ hist_ro,
                             unsigned int* __restrict__ hist) {
    __shared__ unsigned int csum[256];
    __shared__ unsigned int sres[2];
    __shared__ unsigned int lh[2048];
    unsigned int B1, rem_unused;
    radix_sel_256(hist_ro, (unsigned int)K_KEEP, csum, sres, B1, rem_unused);
    for (int t = threadIdx.x; t < 2048; t += 256) lh[t] = 0;
    __syncthreads();
    for (unsigned int i = blockIdx.x * 256 + threadIdx.x; i < NNZ; i += gridDim.x * 256) {
        unsigned int key = __float_as_uint(probs_b[i]);
        if ((key >> 21) == B1) atomicAdd(&lh[(key >> 10) & 2047u], 1u);
    }
    __syncthreads();
    for (int t = threadIdx.x; t < 2048; t += 256)
        if (lh[t]) atomicAdd(&hist[2048 + t], lh[t]);
}

// R7: level-2 selection (old scan_sel which=1) inlined; lo/hi computed locally, persisted
// to st by every block (identical value -> benign race). Then the original two-phase
// n_hi count + band append.
__global__ void bandsel_kernel(const float* __restrict__ probs_b, const int* __restrict__ E,
                               const uint2* __restrict__ vj,
                               const unsigned int* __restrict__ hist,
                               SelState* __restrict__ st,
                               unsigned int* __restrict__ band_p, unsigned int* __restrict__ band_j,
                               unsigned int* __restrict__ band_e, unsigned int* __restrict__ band_v) {
    __shared__ unsigned int csum[256];
    __shared__ unsigned int sres[2];
    __shared__ unsigned int whi[4], wband[4];
    __shared__ unsigned int sbase, scur;
    unsigned int B1, rem1, bin2, rem2_unused;
    radix_sel_256(hist, (unsigned int)K_KEEP, csum, sres, B1, rem1);
    radix_sel_256(hist + 2048, rem1, csum, sres, bin2, rem2_unused);
    unsigned int P = (B1 << 21) | (bin2 << 10);
    float lo = __uint_as_float(P) - DELTA;
    float hi = __uint_as_float(P + 1024u) + DELTA;
    if (threadIdx.x == 0) { st->lo_edge = lo; st->hi_edge = hi; }
    // phase A: local counts
    unsigned int nhi = 0, nband = 0;
    for (unsigned int p = blockIdx.x * 256 + threadIdx.x; p < NNZ; p += gridDim.x * 256) {
        float pk = probs_b[p];
        if (pk > hi) nhi++;
        else if (pk >= lo) nband++;
    }
    #pragma unroll
    for (int o = 32; o > 0; o >>= 1) {
        nhi   += __shfl_down(nhi, o);
        nband += __shfl_down(nband, o);
    }
    if ((threadIdx.x & 63) == 0) { whi[threadIdx.x >> 6] = nhi; wband[threadIdx.x >> 6] = nband; }
    __syncthreads();
    if (threadIdx.x == 0) {
        unsigned int th = whi[0] + whi[1] + whi[2] + whi[3];
        unsigned int tb = wband[0] + wband[1] + wband[2] + wband[3];
        if (th) atomicAdd(&st->n_hi, th);
        sbase = tb ? atomicAdd(&st->band_n, tb) : 0u;
        scur = 0;
    }
    __syncthreads();
    // phase B: append via LDS cursor
    for (unsigned int p = blockIdx.x * 256 + threadIdx.x; p < NNZ; p += gridDim.x * 256) {
        float pk = probs_b[p];
        if (pk <= hi && pk >= lo) {
            unsigned int s = sbase + atomicAdd(&scur, 1u);
            if (s < BANDCAP) {
                uint2 t = vj[p];
                band_p[s] = p;
                band_j[s] = t.y;
                band_e[s] = (unsigned int)E[t.y];
                band_v[s] = t.x;
            }
        }
    }
}

// exact f64 recompute for band members; W1 staged in LDS
__global__ void rescue_kernel(const uint2* __restrict__ vj,
                              const unsigned int* __restrict__ edge_off,
                              const unsigned int* __restrict__ edge_cnt,
                              const float* __restrict__ x, const float* __restrict__ W1,
                              const float* __restrict__ b1, const float* __restrict__ W2,
                              const float* __restrict__ b2,
                              const unsigned int* __restrict__ band_e,
                              const unsigned int* __restrict__ band_v,
                              const SelState* __restrict__ st,
                              unsigned long long* __restrict__ band_key) {
    unsigned int n = st->band_n; if (n > BANDCAP) n = BANDCAP;
    if (blockIdx.x * 8 >= n) return;
    __shared__ float sW[128 * 32];
    for (int t = threadIdx.x; t < 128 * 32; t += 256) sW[t] = W1[t];
    __syncthreads();
    unsigned int g = blockIdx.x * 8 + (threadIdx.x >> 5);
    if (g >= n) return;
    int k = threadIdx.x & 31;
    unsigned int v = band_v[g];
    unsigned int e = band_e[g];
    unsigned int off = edge_off[e];
    unsigned int deg = edge_cnt[e];

    const float* xv = x + (size_t)v * 64u;
    double a = 0.0;
    #pragma unroll 8
    for (int d = 0; d < 64; ++d) a += (double)xv[d] * (double)sW[d * 32 + k];
    double bsum = 0.0;
    for (unsigned int m = off; m < off + deg; ++m) {
        const float* xm = x + (size_t)vj[m].x * 64u;
        double acc = 0.0;
        #pragma unroll 8
        for (int d = 0; d < 64; ++d) acc += (double)xm[d] * (double)sW[(64 + d) * 32 + k];
        bsum += acc;
    }
    double cc = (double)(deg > 1u ? deg : 1u);
    double h = a + bsum / cc + (double)b1[k];
    h = h > 0.0 ? h : 0.0;
    double t = h * (double)W2[k];
    #pragma unroll
    for (int o = 16; o > 0; o >>= 1) t += __shfl_down(t, o, 32);
    if (k == 0) {
        double pr = 1.0 / (1.0 + exp(-(t + (double)b2[0])));
        band_key[g] = (unsigned long long)__double_as_longlong(pr);
    }
}

// ---------------- O(n) band selection: 2-level hist on monotone u32 map ----------------
__global__ void bhist1_kernel(const unsigned long long* __restrict__ band_key,
                              const SelState* __restrict__ st, unsigned int* __restrict__ hist) {
    __shared__ unsigned int lh[2048];
    for (int t = threadIdx.x; t < 2048; t += 256) lh[t] = 0;
    __syncthreads();
    unsigned int n = st->band_n; if (n > BANDCAP) n = BANDCAP;
    float lo = st->lo_edge;
    for (unsigned int i = blockIdx.x * 256 + threadIdx.x; i < n; i += gridDim.x * 256) {
        unsigned int u = band_u32(__longlong_as_double((long long)band_key[i]), lo);
        atomicAdd(&lh[u >> 21], 1u);
    }
    __syncthreads();
    for (int t = threadIdx.x; t < 2048; t += 256)
        if (lh[t]) atomicAdd(&hist[4096 + t], lh[t]);
}

// R7: band level-1 selection (old bscan which=0) inlined.
__global__ void bhist2_kernel(const unsigned long long* __restrict__ band_key,
                              const SelState* __restrict__ st, unsigned int* __restrict__ hist) {
    __shared__ unsigned int csum[256];
    __shared__ unsigned int sres[2];
    __shared__ unsigned int lh[2048];
    unsigned int bB1, rem_unused;
    radix_sel_256(hist + 4096, (unsigned int)K_KEEP - st->n_hi, csum, sres, bB1, rem_unused);
    for (int t = threadIdx.x; t < 2048; t += 256) lh[t] = 0;
    __syncthreads();
    unsigned int n = st->band_n; if (n > BANDCAP) n = BANDCAP;
    float lo = st->lo_edge;
    for (unsigned int i = blockIdx.x * 256 + threadIdx.x; i < n; i += gridDim.x * 256) {
        unsigned int u = band_u32(__longlong_as_double((long long)band_key[i]), lo);
        if ((u >> 21) == bB1) atomicAdd(&lh[(u >> 10) & 2047u], 1u);
    }
    __syncthreads();
    for (int t = threadIdx.x; t < 2048; t += 256)
        if (lh[t]) atomicAdd(&hist[6144 + t], lh[t]);
}

// R7: both band scans inlined; bU0/brem2 persisted for btierank (identical-value writes).
// mark u >= bU0+1024 selected; collect tie bucket [bU0, bU0+1024)
__global__ void btie_kernel(const unsigned long long* __restrict__ band_key,
                            const unsigned int* __restrict__ band_j,
                            const unsigned int* __restrict__ band_p,
                            const unsigned int* __restrict__ hist,
                            SelState* __restrict__ st, unsigned char* __restrict__ flag,
                            unsigned long long* __restrict__ tie_k,
                            unsigned int* __restrict__ tie_j, unsigned int* __restrict__ tie_p) {
    __shared__ unsigned int csum[256];
    __shared__ unsigned int sres[2];
    unsigned int bB1, brem1, bin2, brem2;
    radix_sel_256(hist + 4096, (unsigned int)K_KEEP - st->n_hi, csum, sres, bB1, brem1);
    radix_sel_256(hist + 6144, brem1, csum, sres, bin2, brem2);
    unsigned int U0 = (bB1 << 21) | (bin2 << 10);
    if (threadIdx.x == 0) { st->bU0 = U0; st->brem2 = brem2; }
    unsigned int n = st->band_n; if (n > BANDCAP) n = BANDCAP;
    unsigned int i = blockIdx.x * 256 + threadIdx.x;
    if (i >= n) return;
    float lo = st->lo_edge;
    unsigned long long key = band_key[i];
    unsigned int u = band_u32(__longlong_as_double((long long)key), lo);
    if (u >= U0 + 1024u) {
        flag[band_p[i]] = 2u;
    } else if (u >= U0) {
        unsigned int s = atomicAdd(&st->tie_n, 1u);
        if (s < TIECAP) { tie_k[s] = key; tie_j[s] = band_j[i]; tie_p[s] = band_p[i]; }
    }
}

// exact rank inside the (tiny) tie bucket by (key desc, j asc); take first brem2
__global__ void btierank_kernel(const unsigned long long* __restrict__ tie_k,
                                const unsigned int* __restrict__ tie_j,
                                const unsigned int* __restrict__ tie_p,
                                const SelState* __restrict__ st, unsigned char* __restrict__ flag) {
    unsigned int n = st->tie_n; if (n > TIECAP) n = TIECAP;
    unsigned int need = st->brem2;
    for (unsigned int i = threadIdx.x; i < n; i += 256) {
        unsigned long long ki = tie_k[i];
        unsigned int ji = tie_j[i];
        unsigned int r = 0;
        for (unsigned int q = 0; q < n; ++q) {
            unsigned long long kq = tie_k[q];
            if (kq > ki || (kq == ki && tie_j[q] < ji)) r++;
        }
        if (r < need) flag[tie_p[i]] = 2u;
    }
}

// j-order coalesced outputs; p recomputed as edge_off[E[j]] + rank[j].
// 4 j's per thread -> 4 independent gathers in flight; float4 stores.
__global__ void out_kernel(const float* __restrict__ probs_b, const unsigned char* __restrict__ flag,
                           const int* __restrict__ E, const unsigned int* __restrict__ rank,
                           const unsigned int* __restrict__ edge_off, const SelState* __restrict__ st,
                           float* __restrict__ o_probs, float* __restrict__ o_soft, float* __restrict__ o_hard) {
    unsigned int j0 = (blockIdx.x * 256 + threadIdx.x) * 4u;
    if (j0 >= NNZ) return;   // NNZ % 4 == 0, full vectors only
    float hi = st->hi_edge;
    int4  e4 = *reinterpret_cast<const int4*>(E + j0);
    uint4 r4 = *reinterpret_cast<const uint4*>(rank + j0);
    unsigned int p0 = edge_off[e4.x] + r4.x;
    unsigned int p1 = edge_off[e4.y] + r4.y;
    unsigned int p2 = edge_off[e4.z] + r4.z;
    unsigned int p3 = edge_off[e4.w] + r4.w;
    float pk0 = probs_b[p0], pk1 = probs_b[p1], pk2 = probs_b[p2], pk3 = probs_b[p3];
    unsigned char f0 = flag[p0], f1 = flag[p1], f2 = flag[p2], f3 = flag[p3];
    float4 pr = make_float4(pk0, pk1, pk2, pk3);
    float4 hb = make_float4((pk0 > hi || f0 == 2u) ? 1.f : 0.f,
                            (pk1 > hi || f1 == 2u) ? 1.f : 0.f,
                            (pk2 > hi || f2 == 2u) ? 1.f : 0.f,
                            (pk3 > hi || f3 == 2u) ? 1.f : 0.f);
    *reinterpret_cast<float4*>(o_probs + j0) = pr;
    *reinterpret_cast<float4*>(o_soft  + j0) = hb;
    *reinterpret_cast<float4*>(o_hard  + j0) = hb;
}

// per-edge: edge_soft / edge_hard recomputed from CSR-coalesced probs/flag
__global__ void edge_out_kernel(const float* __restrict__ probs_b, const unsigned char* __restrict__ flag,
                                const unsigned int* __restrict__ edge_off,
                                const unsigned int* __restrict__ edge_cnt,
                                const SelState* __restrict__ st,
                                float* __restrict__ o_es, float* __restrict__ o_eh) {
    unsigned int e = blockIdx.x * 256 + threadIdx.x;
    if (e >= N_EDGES) return;
    float hi = st->hi_edge;
    unsigned int off = edge_off[e], deg = edge_cnt[e];
    unsigned int cnt = 0;
    for (unsigned int i = 0; i < deg; ++i)
        cnt += (probs_b[off + i] > hi || flag[off + i] == 2u) ? 1u : 0u;
    float cc = (float)(deg > 1u ? deg : 1u);
    o_es[e] = (float)cnt / cc;
    o_eh[e] = cnt ? 1.f : 0.f;
}

extern "C" void kernel_launch(void* const* d_in, const int* in_sizes, int n_in,
                              void* d_out, int out_size, void* d_ws, size_t ws_size,
                              hipStream_t stream) {
    const float* x  = (const float*)d_in[0];
    const int*   V  = (const int*)d_in[1];
    const int*   E  = (const int*)d_in[2];
    const float* W1 = (const float*)d_in[3];
    const float* b1 = (const float*)d_in[4];
    const float* W2 = (const float*)d_in[5];
    const float* b2 = (const float*)d_in[6];

    float* out     = (float*)d_out;
    float* o_probs = out;
    float* o_soft  = out + NNZ;
    float* o_hard  = out + 2 * (size_t)NNZ;
    float* o_ep    = out + 3 * (size_t)NNZ;
    float* o_es    = out + 3 * (size_t)NNZ + N_EDGES;
    float* o_eh    = out + 3 * (size_t)NNZ + 2 * (size_t)N_EDGES;

    char* w = (char*)d_ws;
    float2*             p_ab2    = (float2*)(w + OFF_PAB);
    float*              probs_b  = (float*)(w + OFF_PB32);
    uint2*              vj       = (uint2*)(w + OFF_VJ);
    unsigned int*       rank     = (unsigned int*)(w + OFF_RANK);
    unsigned int*       edge_off = (unsigned int*)(w + OFF_EOFF);
    unsigned int*       bsums    = (unsigned int*)(w + OFF_BS);
    unsigned int*       band_p   = (unsigned int*)(w + OFF_BANDP);
    unsigned int*       band_j   = (unsigned int*)(w + OFF_BANDJ);
    unsigned int*       band_e   = (unsigned int*)(w + OFF_BANDE);
    unsigned int*       band_v   = (unsigned int*)(w + OFF_BANDV);
    unsigned long long* band_key = (unsigned long long*)(w + OFF_BANDK);
    unsigned long long* tie_k    = (unsigned long long*)(w + OFF_TIEK);
    unsigned int*       tie_j    = (unsigned int*)(w + OFF_TIEJ);
    unsigned int*       tie_p    = (unsigned int*)(w + OFF_TIEP);
    unsigned char*      flag     = (unsigned char*)(w + OFF_FLAG);
    unsigned int*       edge_cnt = (unsigned int*)(w + OFF_ECNT);
    unsigned int*       hist     = (unsigned int*)(w + OFF_HIST);
    SelState*           st       = (SelState*)(w + OFF_ST);

    hipMemsetAsync(w + ZERO_OFF, 0, ZERO_LEN, stream);

    proj_kernel<<<(N_NODES + 7) / 8, 256, 0, stream>>>(x, W1, p_ab2);

    count_rank_kernel<<<(NNZ + 2047) / 2048, 256, 0, stream>>>(E, edge_cnt, rank);
    scanA_kernel<<<SCAN_BLOCKS, 256, 0, stream>>>(edge_cnt, edge_off, bsums);
    scanB_kernel<<<1, 256, 0, stream>>>(bsums);
    scanC_kernel<<<(N_EDGES + 255) / 256, 256, 0, stream>>>(edge_off, bsums);
    scatter_kernel<<<SC_BLOCKS, 256, 0, stream>>>(V, E, edge_off, rank, vj);

    edge_logit_kernel<<<(N_EDGES + 3) / 4, 256, 0, stream>>>(vj, edge_off, edge_cnt,
                                                             p_ab2, b1, W2, b2, probs_b, o_ep);

    hist1_kernel<<<1024, 256, 0, stream>>>(probs_b, hist);
    hist2_kernel<<<1024, 256, 0, stream>>>(probs_b, hist, hist);
    bandsel_kernel<<<1024, 256, 0, stream>>>(probs_b, E, vj, hist, st,
                                             band_p, band_j, band_e, band_v);
    rescue_kernel<<<BANDCAP / 8, 256, 0, stream>>>(vj, edge_off, edge_cnt, x, W1, b1, W2, b2,
                                                   band_e, band_v, st, band_key);

    bhist1_kernel<<<64, 256, 0, stream>>>(band_key, st, hist);
    bhist2_kernel<<<64, 256, 0, stream>>>(band_key, st, hist);
    btie_kernel<<<BANDCAP / 256, 256, 0, stream>>>(band_key, band_j, band_p, hist, st, flag,
                                                   tie_k, tie_j, tie_p);
    btierank_kernel<<<1, 256, 0, stream>>>(tie_k, tie_j, tie_p, st, flag);

    out_kernel<<<(NNZ / 4 + 255) / 256, 256, 0, stream>>>(probs_b, flag, E, rank, edge_off, st,
                                                          o_probs, o_soft, o_hard);
    edge_out_kernel<<<(N_EDGES + 255) / 256, 256, 0, stream>>>(probs_b, flag, edge_off, edge_cnt, st,
                                                               o_es, o_eh);
}